// Round 6
// baseline (342.806 us; speedup 1.0000x reference)
//
#include <hip/hip_runtime.h>
#include <hip/hip_bf16.h>

#define BB 8
#define NN 1024
#define HH 512
#define NHEADS 8
#define UU 64

typedef __attribute__((ext_vector_type(8))) short short8;
typedef __attribute__((ext_vector_type(4))) float f32x4;
typedef unsigned short u16;
typedef unsigned char u8;

__device__ inline float b2f(unsigned short u) {
    union { float f; unsigned int i; } c; c.i = ((unsigned int)u) << 16; return c.f;
}
__device__ inline unsigned short f2b(float f) {
    __hip_bfloat16 h = __float2bfloat16(f);
    return *reinterpret_cast<unsigned short*>(&h);
}
// async global->LDS, 16B per lane. lds base wave-uniform; data lands at base + lane*16.
__device__ inline void gl_lds16(const void* g, void* l) {
    __builtin_amdgcn_global_load_lds(
        (const __attribute__((address_space(1))) unsigned int*)g,
        (__attribute__((address_space(3))) unsigned int*)l, 16, 0, 0);
}
__device__ inline u8 f2fp8(float f) {
    return (u8)__builtin_amdgcn_cvt_pk_fp8_f32(f, f, 0, false);
}

// ---------------------------------------------------------------------------
// K0: fp32 -> bf16. blockIdx.y: 0=x, 1..3=Wq/Wk/Wv.
// ---------------------------------------------------------------------------
__global__ __launch_bounds__(256) void cvt_bf16(
    const float* __restrict__ x, const float* __restrict__ Wq,
    const float* __restrict__ Wk, const float* __restrict__ Wv,
    u16* __restrict__ xb, u16* __restrict__ Wb)
{
    const int which = blockIdx.y;
    const float* src;
    u16* dst;
    int n;
    if (which == 0) { src = x;  dst = xb;              n = BB * NN * HH; }
    else if (which == 1) { src = Wq; dst = Wb;             n = HH * HH; }
    else if (which == 2) { src = Wk; dst = Wb + HH * HH;   n = HH * HH; }
    else              { src = Wv; dst = Wb + 2 * HH * HH;  n = HH * HH; }

    const int base = (blockIdx.x * 256 + threadIdx.x) * 8;
    if (base >= n) return;
    const float4* sp = (const float4*)&src[base];
    float4 a = sp[0], b = sp[1];
    short8 o;
    o[0] = (short)f2b(a.x); o[1] = (short)f2b(a.y);
    o[2] = (short)f2b(a.z); o[3] = (short)f2b(a.w);
    o[4] = (short)f2b(b.x); o[5] = (short)f2b(b.y);
    o[6] = (short)f2b(b.z); o[7] = (short)f2b(b.w);
    *(short8*)&dst[base] = o;
}

// ---------------------------------------------------------------------------
// K0b: pack adj (int32 0/1) into bitmask adjp[row(8192)][dword(32)].
// ---------------------------------------------------------------------------
__global__ __launch_bounds__(256) void adj_pack(
    const int* __restrict__ adj, unsigned int* __restrict__ adjp)
{
    const int wave = threadIdx.x >> 6, lane = threadIdx.x & 63;
    const int row = blockIdx.x * 4 + wave;       // b*N + n
    const int* ar = adj + (size_t)row * NN;
    unsigned long long* out = (unsigned long long*)(adjp + (size_t)row * 32);
    #pragma unroll
    for (int it = 0; it < 16; ++it) {
        int a = ar[it * 64 + lane];
        unsigned long long m = __ballot(a != 0);
        if (lane == 0) out[it] = m;
    }
}

// ---------------------------------------------------------------------------
// K1: y = x @ W^T + b (q,k,v via blockIdx.z). 128x128 tile, BK=32,
// global_load_lds staging. C staged through LDS -> 128B-contiguous stores.
// Output per-head layout: out[(b*8+h)*1024+n][64].
// ---------------------------------------------------------------------------
__global__ __launch_bounds__(256) void qkv_gemm(
    const u16* __restrict__ xb, const u16* __restrict__ Wb,
    const float* __restrict__ bq, const float* __restrict__ bk,
    const float* __restrict__ bv,
    u16* __restrict__ q, u16* __restrict__ k, u16* __restrict__ v)
{
    const int which = blockIdx.z;
    const u16* W      = Wb + which * HH * HH;
    const float* bias = which == 0 ? bq : (which == 1 ? bk : bv);
    u16* out          = which == 0 ? q  : (which == 1 ? k  : v);

    const int tid = threadIdx.x;
    const int wave = tid >> 6, lane = tid & 63;
    const int ln = lane & 15, quad = lane >> 4;
    const int wr = (wave >> 1) * 64, wc = (wave & 1) * 64;
    const int rowbase = blockIdx.x * 128, colbase = blockIdx.y * 128;

    __shared__ __align__(16) u16 As[128 * 32];
    __shared__ __align__(16) u16 Bs[128 * 32];
    __shared__ __align__(16) u16 Cs[128 * 136];   // +8 pad: 16B align + bank spread

    f32x4 acc[4][4];
    #pragma unroll
    for (int ri = 0; ri < 4; ++ri)
        #pragma unroll
        for (int ci = 0; ci < 4; ++ci) acc[ri][ci] = (f32x4){0.f, 0.f, 0.f, 0.f};

    const int lr = lane >> 2;
    const int lk = (lane & 3) * 8;

    for (int kk = 0; kk < HH; kk += 32) {
        __syncthreads();
        #pragma unroll
        for (int i = 0; i < 2; ++i) {
            int r = wave * 32 + i * 16 + lr;
            gl_lds16(&xb[(size_t)(rowbase + r) * HH + kk + lk],
                     (char*)As + (wave * 32 + i * 16) * 64);
            gl_lds16(&W[(size_t)(colbase + r) * HH + kk + lk],
                     (char*)Bs + (wave * 32 + i * 16) * 64);
        }
        __syncthreads();

        short8 bfr[4];
        #pragma unroll
        for (int ci = 0; ci < 4; ++ci)
            bfr[ci] = *(const short8*)&Bs[(wc + ci * 16 + ln) * 32 + quad * 8];
        #pragma unroll
        for (int ri = 0; ri < 4; ++ri) {
            short8 af = *(const short8*)&As[(wr + ri * 16 + ln) * 32 + quad * 8];
            #pragma unroll
            for (int ci = 0; ci < 4; ++ci)
                acc[ri][ci] = __builtin_amdgcn_mfma_f32_16x16x32_bf16(af, bfr[ci], acc[ri][ci], 0, 0, 0);
        }
    }

    // stage C in LDS
    #pragma unroll
    for (int ci = 0; ci < 4; ++ci) {
        int col = wc + ci * 16 + ln;          // local 0..127
        float bb = bias[colbase + col];
        #pragma unroll
        for (int ri = 0; ri < 4; ++ri) {
            #pragma unroll
            for (int r = 0; r < 4; ++r) {
                int row = wr + ri * 16 + quad * 4 + r;
                Cs[row * 136 + col] = f2b(acc[ri][ci][r] + bb);
            }
        }
    }
    __syncthreads();

    // coalesced store: thread -> (row, 64-col half); 128 B contiguous each
    {
        int row = tid >> 1, half = tid & 1;
        int gcol0 = colbase + half * 64;
        int hh = gcol0 >> 6;
        int grow = rowbase + row;
        int bidx = grow >> 10, n = grow & 1023;
        u16* op = &out[(((size_t)(bidx * NHEADS + hh)) * NN + n) * UU];
        const u16* cp = &Cs[row * 136 + half * 64];
        #pragma unroll
        for (int j = 0; j < 8; ++j)
            *(short8*)(op + j * 8) = *(const short8*)(cp + j * 8);
    }
}

// ---------------------------------------------------------------------------
// K2b: v (per-head bf16 [bh][n][64]) -> v^T fp8: v8t[bh][d(64)][n(1024)].
// ---------------------------------------------------------------------------
__global__ __launch_bounds__(256) void vt8(
    const u16* __restrict__ v, u8* __restrict__ v8t)
{
    const int bh = blockIdx.x;
    const int t = threadIdx.x;
    const size_t hd = (size_t)bh << 16;
    __shared__ u16 tile[64][72];

    for (int chunk = 0; chunk < 16; ++chunk) {
        const int n0 = chunk * 64;
        const int r = t >> 2, cs = t & 3;
        const u16* vp = &v[((size_t)bh * NN + n0 + r) * UU + cs * 16];
        short8 a = *(const short8*)vp;
        short8 b8 = *(const short8*)(vp + 8);
        #pragma unroll
        for (int j = 0; j < 8; ++j) {
            tile[r][cs * 16 + j] = (u16)a[j];
            tile[r][cs * 16 + 8 + j] = (u16)b8[j];
        }
        __syncthreads();
        const int c = t & 63, qt = t >> 6;
        unsigned int w[4];
        #pragma unroll
        for (int g = 0; g < 4; ++g) {
            float f0 = b2f(tile[qt * 16 + g * 4 + 0][c]);
            float f1 = b2f(tile[qt * 16 + g * 4 + 1][c]);
            float f2 = b2f(tile[qt * 16 + g * 4 + 2][c]);
            float f3 = b2f(tile[qt * 16 + g * 4 + 3][c]);
            int lo = __builtin_amdgcn_cvt_pk_fp8_f32(f0, f1, 0, false);
            w[g] = (unsigned int)__builtin_amdgcn_cvt_pk_fp8_f32(f2, f3, lo, true);
        }
        uint4 o; o.x = w[0]; o.y = w[1]; o.z = w[2]; o.w = w[3];
        *(uint4*)&v8t[hd + (size_t)c * 1024 + n0 + qt * 16] = o;
        __syncthreads();
    }
}

// ---------------------------------------------------------------------------
// K2: per (b,h,rt): S = q_h @ k_h^T (16 rows x 1024), bitmask, softmax
// (constant-shift exp), P fp8 x16 staged in LDS -> coalesced global write,
// THEN fused hop-1 using the P-tile still in LDS:
//   z1 = 0.05625 * (P16 @ z0) + 0.1 * v,  z0 = v8t (fp8), output z1^T fp8.
// ---------------------------------------------------------------------------
__global__ __launch_bounds__(256) void scores_softmax_h1(
    const u16* __restrict__ q, const u16* __restrict__ kmat,
    const unsigned int* __restrict__ adjp, const u8* __restrict__ v8t,
    const u16* __restrict__ v, u8* __restrict__ P8, u8* __restrict__ z8out)
{
    const int b = blockIdx.z, h = blockIdx.y, rt = blockIdx.x;
    const int bh = b * NHEADS + h;
    const int wave = threadIdx.x >> 6, lane = threadIdx.x & 63;
    const int ln = lane & 15, quad = lane >> 4;
    const int rowbase = rt * 16;

    __shared__ float redsum[4][16];
    __shared__ __align__(16) u8 Pst[16384];

    const u16* qp = &q[((size_t)bh * NN + rowbase + ln) * UU + quad * 8];
    short8 a0 = *(const short8*)qp;
    short8 a1 = *(const short8*)(qp + 32);

    unsigned int abits[4][8];
    #pragma unroll
    for (int r = 0; r < 4; ++r) {
        int row = rowbase + quad * 4 + r;
        const uint4* ap = (const uint4*)&adjp[((size_t)(b * NN + row)) * 32 + wave * 8];
        *(uint4*)&abits[r][0] = ap[0];
        *(uint4*)&abits[r][4] = ap[1];
    }

    f32x4 accs[16];
    #pragma unroll
    for (int ct = 0; ct < 16; ++ct) {
        int col = wave * 256 + ct * 16 + ln;
        const u16* kp = &kmat[((size_t)bh * NN + col) * UU + quad * 8];
        short8 b0 = *(const short8*)kp;
        short8 b1 = *(const short8*)(kp + 32);
        f32x4 acc = (f32x4){0.f, 0.f, 0.f, 0.f};
        acc = __builtin_amdgcn_mfma_f32_16x16x32_bf16(a0, b0, acc, 0, 0, 0);
        acc = __builtin_amdgcn_mfma_f32_16x16x32_bf16(a1, b1, acc, 0, 0, 0);
        accs[ct] = acc;
    }

    float rsum[4] = {0.f, 0.f, 0.f, 0.f};
    #pragma unroll
    for (int ct = 0; ct < 16; ++ct) {
        const int kc8 = ct >> 1;
        const int bitpos = (ct & 1) * 16 + ln;
        #pragma unroll
        for (int r = 0; r < 4; ++r) {
            unsigned int on = (abits[r][kc8] >> bitpos) & 1u;
            float e = on ? __expf(accs[ct][r] - 32.0f) : 0.0f;
            accs[ct][r] = e;
            rsum[r] += e;
        }
    }
    #pragma unroll
    for (int r = 0; r < 4; ++r) {
        #pragma unroll
        for (int off = 8; off >= 1; off >>= 1)
            rsum[r] += __shfl_xor(rsum[r], off);
    }
    if (ln == 0) {
        #pragma unroll
        for (int r = 0; r < 4; ++r) redsum[wave][quad * 4 + r] = rsum[r];
    }
    __syncthreads();
    float sc16[4];
    #pragma unroll
    for (int r = 0; r < 4; ++r) {
        int row16 = quad * 4 + r;
        float s = redsum[0][row16] + redsum[1][row16] + redsum[2][row16] + redsum[3][row16];
        sc16[r] = 16.0f / s;
    }

    // stage fp8 P-tile in LDS: Pst[kc(32)][row(16)][cb(32)]
    #pragma unroll
    for (int ct = 0; ct < 16; ++ct) {
        int kc = wave * 8 + (ct >> 1);
        int cb = (ct & 1) * 16 + ln;
        #pragma unroll
        for (int r = 0; r < 4; ++r)
            Pst[kc * 512 + (quad * 4 + r) * 32 + cb] = f2fp8(accs[ct][r] * sc16[r]);
    }
    __syncthreads();

    // coalesced copy LDS -> global (16 KB per block)
    {
        u8* Pb = P8 + ((size_t)bh << 20) + rt * 16384;
        const uint4* srcp = (const uint4*)(Pst + threadIdx.x * 64);
        uint4* dstp = (uint4*)(Pb + threadIdx.x * 64);
        dstp[0] = srcp[0]; dstp[1] = srcp[1]; dstp[2] = srcp[2]; dstp[3] = srcp[3];
    }

    // ---- fused hop-1: wave w covers d in [w*16, +16), rows = this block's 16.
    {
        const u8* vt = v8t + ((size_t)bh << 16);
        const int dcol = wave * 16 + ln;
        f32x4 h1 = (f32x4){0.f, 0.f, 0.f, 0.f};
        #pragma unroll 4
        for (int kc = 0; kc < 32; ++kc) {
            long a = *(const long*)&Pst[kc * 512 + ln * 32 + quad * 8];
            long bz = *(const long*)&vt[(size_t)dcol * 1024 + kc * 32 + quad * 8];
            h1 = __builtin_amdgcn_mfma_f32_16x16x32_fp8_fp8(a, bz, h1, 0, 0, 0);
        }
        const int n0 = rowbase + quad * 4;
        float zv[4];
        #pragma unroll
        for (int r = 0; r < 4; ++r) {
            float vv = b2f(v[((size_t)bh * NN + n0 + r) * UU + dcol]);
            zv[r] = 0.05625f * h1[r] + 0.1f * vv;
        }
        int lo = __builtin_amdgcn_cvt_pk_fp8_f32(zv[0], zv[1], 0, false);
        unsigned int dw = (unsigned int)__builtin_amdgcn_cvt_pk_fp8_f32(zv[2], zv[3], lo, true);
        *(unsigned int*)&z8out[((size_t)bh << 16) + (size_t)dcol * 1024 + n0] = dw;
    }
}

// ---------------------------------------------------------------------------
// K3: hop: z' = (0.9/16) * P16 @ z + 0.1 * v.
// last=0: write z'^T fp8;  last=1: write z' bf16 in [b,n,512] layout.
// ---------------------------------------------------------------------------
__global__ __launch_bounds__(512) void hop(
    const u8* __restrict__ P8, const u8* __restrict__ z8in,
    const u16* __restrict__ v, u8* __restrict__ z8out,
    u16* __restrict__ zbf_out, int last)
{
    const int b = blockIdx.z, h = blockIdx.y, rt = blockIdx.x;
    const int bh = b * NHEADS + h;
    const int tid = threadIdx.x;
    const int wave = tid >> 6, lane = tid & 63;
    const int ln = lane & 15, quad = lane >> 4;
    const int wrow = rt * 128 + wave * 16;

    __shared__ __align__(16) u8 zt[64 * 1040];

    const u8* zg = z8in + ((size_t)bh << 16);
    #pragma unroll
    for (int i = 0; i < 8; ++i) {
        int c = wave * 8 + i;
        gl_lds16(zg + (size_t)c * 1024 + lane * 16, (char*)zt + c * 1040);
    }
    __syncthreads();

    f32x4 acc[4];
    #pragma unroll
    for (int ci = 0; ci < 4; ++ci) acc[ci] = (f32x4){0.f, 0.f, 0.f, 0.f};

    const u8* pt = P8 + ((size_t)bh << 20) + (size_t)(rt * 8 + wave) * 16384
                 + ln * 32 + quad * 8;
    #pragma unroll 4
    for (int kc = 0; kc < 32; ++kc) {
        long a = *(const long*)(pt + kc * 512);
        int kk = kc * 32;
        #pragma unroll
        for (int ci = 0; ci < 4; ++ci) {
            long bz = *(const long*)&zt[(ci * 16 + ln) * 1040 + kk + quad * 8];
            acc[ci] = __builtin_amdgcn_mfma_f32_16x16x32_fp8_fp8(a, bz, acc[ci], 0, 0, 0);
        }
    }

    if (last) {
        #pragma unroll
        for (int ci = 0; ci < 4; ++ci) {
            int col = ci * 16 + ln;
            #pragma unroll
            for (int r = 0; r < 4; ++r) {
                int row = wrow + quad * 4 + r;
                float vv = b2f(v[((size_t)bh * NN + row) * UU + col]);
                zbf_out[((size_t)(b * NN + row)) * HH + h * UU + col]
                    = f2b(0.05625f * acc[ci][r] + 0.1f * vv);
            }
        }
    } else {
        u8* zo = z8out + ((size_t)bh << 16);
        #pragma unroll
        for (int ci = 0; ci < 4; ++ci) {
            int col = ci * 16 + ln;
            float zv[4];
            #pragma unroll
            for (int r = 0; r < 4; ++r) {
                int row = wrow + quad * 4 + r;
                float vv = b2f(v[((size_t)bh * NN + row) * UU + col]);
                zv[r] = 0.05625f * acc[ci][r] + 0.1f * vv;
            }
            int lo = __builtin_amdgcn_cvt_pk_fp8_f32(zv[0], zv[1], 0, false);
            unsigned int dw = (unsigned int)__builtin_amdgcn_cvt_pk_fp8_f32(zv[2], zv[3], lo, true);
            *(unsigned int*)&zo[(size_t)col * 1024 + wrow + quad * 4] = dw;
        }
    }
}

// ---------------------------------------------------------------------------
// K4: y = x + z ; LayerNorm(y)*gamma + beta. x fp32, z bf16 [b,n,512], out fp32.
// ---------------------------------------------------------------------------
__global__ __launch_bounds__(256) void resid_ln(
    const float* __restrict__ x, const u16* __restrict__ z,
    const float* __restrict__ gamma, const float* __restrict__ beta,
    float* __restrict__ out)
{
    const int r = blockIdx.x * 4 + (threadIdx.x >> 6);
    const int lane = threadIdx.x & 63;
    const size_t base = (size_t)r * HH + lane * 8;

    const float4* xp = (const float4*)&x[base];
    float4 x0 = xp[0], x1 = xp[1];
    short8 zv = *(const short8*)&z[base];
    float y[8];
    y[0] = x0.x + b2f((u16)zv[0]); y[1] = x0.y + b2f((u16)zv[1]);
    y[2] = x0.z + b2f((u16)zv[2]); y[3] = x0.w + b2f((u16)zv[3]);
    y[4] = x1.x + b2f((u16)zv[4]); y[5] = x1.y + b2f((u16)zv[5]);
    y[6] = x1.z + b2f((u16)zv[6]); y[7] = x1.w + b2f((u16)zv[7]);

    float s = 0.f, sq = 0.f;
    #pragma unroll
    for (int j = 0; j < 8; ++j) { s += y[j]; sq += y[j] * y[j]; }
    #pragma unroll
    for (int off = 32; off >= 1; off >>= 1) {
        s  += __shfl_xor(s, off);
        sq += __shfl_xor(sq, off);
    }
    const float mu = s * (1.0f / HH);
    const float var = sq * (1.0f / HH) - mu * mu;
    const float rstd = rsqrtf(var + 1e-5f);

    const float4* gp = (const float4*)&gamma[lane * 8];
    const float4* bp = (const float4*)&beta[lane * 8];
    float4 g0 = gp[0], g1 = gp[1], b0 = bp[0], b1 = bp[1];

    float4 o0, o1;
    o0.x = (y[0] - mu) * rstd * g0.x + b0.x;
    o0.y = (y[1] - mu) * rstd * g0.y + b0.y;
    o0.z = (y[2] - mu) * rstd * g0.z + b0.z;
    o0.w = (y[3] - mu) * rstd * g0.w + b0.w;
    o1.x = (y[4] - mu) * rstd * g1.x + b1.x;
    o1.y = (y[5] - mu) * rstd * g1.y + b1.y;
    o1.z = (y[6] - mu) * rstd * g1.z + b1.z;
    o1.w = (y[7] - mu) * rstd * g1.w + b1.w;
    float4* op = (float4*)&out[base];
    op[0] = o0; op[1] = o1;
}

// ---------------------------------------------------------------------------
extern "C" void kernel_launch(void* const* d_in, const int* in_sizes, int n_in,
                              void* d_out, int out_size, void* d_ws, size_t ws_size,
                              hipStream_t stream)
{
    const float* x   = (const float*)d_in[0];
    const int* adj   = (const int*)d_in[1];
    const float* Wq  = (const float*)d_in[2];
    const float* bq  = (const float*)d_in[3];
    const float* Wk  = (const float*)d_in[4];
    const float* bk  = (const float*)d_in[5];
    const float* Wv  = (const float*)d_in[6];
    const float* bv  = (const float*)d_in[7];
    const float* gamma = (const float*)d_in[8];
    const float* beta  = (const float*)d_in[9];
    float* out = (float*)d_out;

    const size_t E = (size_t)BB * NN * HH;   // 4,194,304
    u16* ws16 = (u16*)d_ws;
    u16* xb = ws16;
    u16* q  = ws16 + E;      // per-head layout [bh][n][64]
    u16* k  = ws16 + 2 * E;  // per-head layout
    u16* v  = ws16 + 3 * E;  // per-head layout
    u16* za = ws16 + 4 * E;  // final z, bf16, [b,n,512]
    u16* Wb = ws16 + 5 * E;  // 786,432 elems
    u8* base8 = (u8*)(ws16 + 5 * E + 786432);
    u8* P8  = base8;                          // 64 MB, tiled layout
    u8* z8a = base8 + ((size_t)64 << 20);     // 4 MB
    u8* z8b = z8a + ((size_t)4 << 20);        // 4 MB
    u8* v8t = z8b + ((size_t)4 << 20);        // 4 MB
    unsigned int* adjp = (unsigned int*)(v8t + ((size_t)4 << 20));  // 1 MB

    cvt_bf16<<<dim3(2048, 4), 256, 0, stream>>>(x, Wq, Wk, Wv, xb, Wb);
    adj_pack<<<dim3(2048), 256, 0, stream>>>(adj, adjp);
    qkv_gemm<<<dim3(64, 4, 3), 256, 0, stream>>>(xb, Wb, bq, bk, bv, q, k, v);
    vt8<<<dim3(64), 256, 0, stream>>>(v, v8t);
    // scores + softmax + P write + hop-1 fused (z1 -> z8a)
    scores_softmax_h1<<<dim3(64, NHEADS, BB), 256, 0, stream>>>(q, k, adjp, v8t, v, P8, z8a);
    // hops 2..4
    hop<<<dim3(8, NHEADS, BB), 512, 0, stream>>>(P8, z8a, v, z8b, za, 0);
    hop<<<dim3(8, NHEADS, BB), 512, 0, stream>>>(P8, z8b, v, z8a, za, 0);
    hop<<<dim3(8, NHEADS, BB), 512, 0, stream>>>(P8, z8a, v, z8b, za, 1);
    resid_ln<<<dim3(2048), 256, 0, stream>>>(x, za, gamma, beta, out);
}

// Round 7
// 312.083 us; speedup vs baseline: 1.0984x; 1.0984x over previous
//
#include <hip/hip_runtime.h>
#include <hip/hip_bf16.h>

#define BB 8
#define NN 1024
#define HH 512
#define NHEADS 8
#define UU 64

typedef __attribute__((ext_vector_type(8))) short short8;
typedef __attribute__((ext_vector_type(4))) float f32x4;
typedef unsigned short u16;
typedef unsigned char u8;

__device__ inline float b2f(unsigned short u) {
    union { float f; unsigned int i; } c; c.i = ((unsigned int)u) << 16; return c.f;
}
__device__ inline unsigned short f2b(float f) {
    __hip_bfloat16 h = __float2bfloat16(f);
    return *reinterpret_cast<unsigned short*>(&h);
}
// async global->LDS, 16B per lane. lds base wave-uniform; data lands at base + lane*16.
__device__ inline void gl_lds16(const void* g, void* l) {
    __builtin_amdgcn_global_load_lds(
        (const __attribute__((address_space(1))) unsigned int*)g,
        (__attribute__((address_space(3))) unsigned int*)l, 16, 0, 0);
}

// ---------------------------------------------------------------------------
// K0: fp32 -> bf16. blockIdx.y: 0=x, 1..3=Wq/Wk/Wv.
// ---------------------------------------------------------------------------
__global__ __launch_bounds__(256) void cvt_bf16(
    const float* __restrict__ x, const float* __restrict__ Wq,
    const float* __restrict__ Wk, const float* __restrict__ Wv,
    u16* __restrict__ xb, u16* __restrict__ Wb)
{
    const int which = blockIdx.y;
    const float* src;
    u16* dst;
    int n;
    if (which == 0) { src = x;  dst = xb;              n = BB * NN * HH; }
    else if (which == 1) { src = Wq; dst = Wb;             n = HH * HH; }
    else if (which == 2) { src = Wk; dst = Wb + HH * HH;   n = HH * HH; }
    else              { src = Wv; dst = Wb + 2 * HH * HH;  n = HH * HH; }

    const int base = (blockIdx.x * 256 + threadIdx.x) * 8;
    if (base >= n) return;
    const float4* sp = (const float4*)&src[base];
    float4 a = sp[0], b = sp[1];
    short8 o;
    o[0] = (short)f2b(a.x); o[1] = (short)f2b(a.y);
    o[2] = (short)f2b(a.z); o[3] = (short)f2b(a.w);
    o[4] = (short)f2b(b.x); o[5] = (short)f2b(b.y);
    o[6] = (short)f2b(b.z); o[7] = (short)f2b(b.w);
    *(short8*)&dst[base] = o;
}

// ---------------------------------------------------------------------------
// K0b: pack adj (int32 0/1) into bitmask adjp[row(8192)][dword(32)].
// ---------------------------------------------------------------------------
__global__ __launch_bounds__(256) void adj_pack(
    const int* __restrict__ adj, unsigned int* __restrict__ adjp)
{
    const int wave = threadIdx.x >> 6, lane = threadIdx.x & 63;
    const int row = blockIdx.x * 4 + wave;       // b*N + n
    const int* ar = adj + (size_t)row * NN;
    unsigned long long* out = (unsigned long long*)(adjp + (size_t)row * 32);
    #pragma unroll
    for (int it = 0; it < 16; ++it) {
        int a = ar[it * 64 + lane];
        unsigned long long m = __ballot(a != 0);
        if (lane == 0) out[it] = m;
    }
}

// ---------------------------------------------------------------------------
// K1: y = x @ W^T + b (q,k,v via blockIdx.z). 128x128 tile, BK=32,
// global_load_lds staging, LDS-staged C -> 128B-contiguous stores.
// Output per-head layout: out[(b*8+h)*1024+n][64].
// ---------------------------------------------------------------------------
__global__ __launch_bounds__(256) void qkv_gemm(
    const u16* __restrict__ xb, const u16* __restrict__ Wb,
    const float* __restrict__ bq, const float* __restrict__ bk,
    const float* __restrict__ bv,
    u16* __restrict__ q, u16* __restrict__ k, u16* __restrict__ v)
{
    const int which = blockIdx.z;
    const u16* W      = Wb + which * HH * HH;
    const float* bias = which == 0 ? bq : (which == 1 ? bk : bv);
    u16* out          = which == 0 ? q  : (which == 1 ? k  : v);

    const int tid = threadIdx.x;
    const int wave = tid >> 6, lane = tid & 63;
    const int ln = lane & 15, quad = lane >> 4;
    const int wr = (wave >> 1) * 64, wc = (wave & 1) * 64;
    const int rowbase = blockIdx.x * 128, colbase = blockIdx.y * 128;

    __shared__ __align__(16) u16 As[128 * 32];
    __shared__ __align__(16) u16 Bs[128 * 32];
    __shared__ __align__(16) u16 Cs[128 * 136];

    f32x4 acc[4][4];
    #pragma unroll
    for (int ri = 0; ri < 4; ++ri)
        #pragma unroll
        for (int ci = 0; ci < 4; ++ci) acc[ri][ci] = (f32x4){0.f, 0.f, 0.f, 0.f};

    const int lr = lane >> 2;
    const int lk = (lane & 3) * 8;

    for (int kk = 0; kk < HH; kk += 32) {
        __syncthreads();
        #pragma unroll
        for (int i = 0; i < 2; ++i) {
            int r = wave * 32 + i * 16 + lr;
            gl_lds16(&xb[(size_t)(rowbase + r) * HH + kk + lk],
                     (char*)As + (wave * 32 + i * 16) * 64);
            gl_lds16(&W[(size_t)(colbase + r) * HH + kk + lk],
                     (char*)Bs + (wave * 32 + i * 16) * 64);
        }
        __syncthreads();

        short8 bfr[4];
        #pragma unroll
        for (int ci = 0; ci < 4; ++ci)
            bfr[ci] = *(const short8*)&Bs[(wc + ci * 16 + ln) * 32 + quad * 8];
        #pragma unroll
        for (int ri = 0; ri < 4; ++ri) {
            short8 af = *(const short8*)&As[(wr + ri * 16 + ln) * 32 + quad * 8];
            #pragma unroll
            for (int ci = 0; ci < 4; ++ci)
                acc[ri][ci] = __builtin_amdgcn_mfma_f32_16x16x32_bf16(af, bfr[ci], acc[ri][ci], 0, 0, 0);
        }
    }

    #pragma unroll
    for (int ci = 0; ci < 4; ++ci) {
        int col = wc + ci * 16 + ln;
        float bb = bias[colbase + col];
        #pragma unroll
        for (int ri = 0; ri < 4; ++ri) {
            #pragma unroll
            for (int r = 0; r < 4; ++r) {
                int row = wr + ri * 16 + quad * 4 + r;
                Cs[row * 136 + col] = f2b(acc[ri][ci][r] + bb);
            }
        }
    }
    __syncthreads();
    {
        int row = tid >> 1, half = tid & 1;
        int gcol0 = colbase + half * 64;
        int hh = gcol0 >> 6;
        int grow = rowbase + row;
        int bidx = grow >> 10, n = grow & 1023;
        u16* op = &out[(((size_t)(bidx * NHEADS + hh)) * NN + n) * UU];
        const u16* cp = &Cs[row * 136 + half * 64];
        #pragma unroll
        for (int j = 0; j < 8; ++j)
            *(short8*)(op + j * 8) = *(const short8*)(cp + j * 8);
    }
}

// ---------------------------------------------------------------------------
// K2b: v (per-head bf16 [bh][n][64]) -> v^T fp8: v8t[bh][d(64)][n(1024)].
// ---------------------------------------------------------------------------
__global__ __launch_bounds__(256) void vt8(
    const u16* __restrict__ v, u8* __restrict__ v8t)
{
    const int bh = blockIdx.x;
    const int t = threadIdx.x;
    const size_t hd = (size_t)bh << 16;
    __shared__ u16 tile[64][72];

    for (int chunk = 0; chunk < 16; ++chunk) {
        const int n0 = chunk * 64;
        const int r = t >> 2, cs = t & 3;
        const u16* vp = &v[((size_t)bh * NN + n0 + r) * UU + cs * 16];
        short8 a = *(const short8*)vp;
        short8 b8 = *(const short8*)(vp + 8);
        #pragma unroll
        for (int j = 0; j < 8; ++j) {
            tile[r][cs * 16 + j] = (u16)a[j];
            tile[r][cs * 16 + 8 + j] = (u16)b8[j];
        }
        __syncthreads();
        const int c = t & 63, qt = t >> 6;
        unsigned int w[4];
        #pragma unroll
        for (int g = 0; g < 4; ++g) {
            float f0 = b2f(tile[qt * 16 + g * 4 + 0][c]);
            float f1 = b2f(tile[qt * 16 + g * 4 + 1][c]);
            float f2 = b2f(tile[qt * 16 + g * 4 + 2][c]);
            float f3 = b2f(tile[qt * 16 + g * 4 + 3][c]);
            int lo = __builtin_amdgcn_cvt_pk_fp8_f32(f0, f1, 0, false);
            w[g] = (unsigned int)__builtin_amdgcn_cvt_pk_fp8_f32(f2, f3, lo, true);
        }
        uint4 o; o.x = w[0]; o.y = w[1]; o.z = w[2]; o.w = w[3];
        *(uint4*)&v8t[hd + (size_t)c * 1024 + n0 + qt * 16] = o;
        __syncthreads();
    }
}

// ---------------------------------------------------------------------------
// K2: per (b,h,rt16): S = q_h @ k_h^T, bitmask, constant-shift softmax.
// Two column-halves with only accs[8] live (register relief -> load ILP);
// e staged in LDS bf16; final coalesced scale->fp8->pack->store of the
// P-tile in MFMA-tile layout P8[bh][rt][kc(32)][r16(16)][cb(32)].
// ---------------------------------------------------------------------------
__global__ __launch_bounds__(256, 4) void scores_softmax(
    const u16* __restrict__ q, const u16* __restrict__ kmat,
    const unsigned int* __restrict__ adjp, u8* __restrict__ P8)
{
    const int b = blockIdx.z, h = blockIdx.y, rt = blockIdx.x;
    const int bh = b * NHEADS + h;
    const int wave = threadIdx.x >> 6, lane = threadIdx.x & 63;
    const int ln = lane & 15, quad = lane >> 4;
    const int rowbase = rt * 16;

    __shared__ float redsum[4][16];
    __shared__ float scl[16];
    __shared__ __align__(16) u16 ebuf[16 * 1040];   // 16 rows, pitch 1040

    const u16* qp = &q[((size_t)bh * NN + rowbase + ln) * UU + quad * 8];
    short8 a0 = *(const short8*)qp;
    short8 a1 = *(const short8*)(qp + 32);

    float rsum[4] = {0.f, 0.f, 0.f, 0.f};

    #pragma unroll
    for (int hf = 0; hf < 2; ++hf) {
        // adj bits for this half's 128 cols (broadcast loads)
        unsigned int ab[4][4];
        #pragma unroll
        for (int r = 0; r < 4; ++r) {
            int row = rowbase + quad * 4 + r;
            *(uint4*)&ab[r][0] =
                *(const uint4*)&adjp[((size_t)(b * NN + row)) * 32 + wave * 8 + hf * 4];
        }

        f32x4 accs[8];
        #pragma unroll
        for (int ct = 0; ct < 8; ++ct) {
            int col = wave * 256 + hf * 128 + ct * 16 + ln;
            const u16* kp = &kmat[((size_t)bh * NN + col) * UU + quad * 8];
            short8 b0 = *(const short8*)kp;
            short8 b1 = *(const short8*)(kp + 32);
            f32x4 acc = (f32x4){0.f, 0.f, 0.f, 0.f};
            acc = __builtin_amdgcn_mfma_f32_16x16x32_bf16(a0, b0, acc, 0, 0, 0);
            acc = __builtin_amdgcn_mfma_f32_16x16x32_bf16(a1, b1, acc, 0, 0, 0);
            accs[ct] = acc;
        }

        #pragma unroll
        for (int ct = 0; ct < 8; ++ct) {
            const int dw = ct >> 1;
            const int bitpos = (ct & 1) * 16 + ln;
            const int col = wave * 256 + hf * 128 + ct * 16 + ln;
            #pragma unroll
            for (int r = 0; r < 4; ++r) {
                unsigned int on = (ab[r][dw] >> bitpos) & 1u;
                float e = on ? __expf(accs[ct][r] - 32.0f) : 0.0f;
                rsum[r] += e;
                ebuf[(quad * 4 + r) * 1040 + col] = f2b(e);
            }
        }
    }

    #pragma unroll
    for (int r = 0; r < 4; ++r) {
        #pragma unroll
        for (int off = 8; off >= 1; off >>= 1)
            rsum[r] += __shfl_xor(rsum[r], off);
    }
    if (ln == 0) {
        #pragma unroll
        for (int r = 0; r < 4; ++r) redsum[wave][quad * 4 + r] = rsum[r];
    }
    __syncthreads();
    if (wave == 0 && ln == 0) {
        #pragma unroll
        for (int r = 0; r < 4; ++r) {
            int row16 = quad * 4 + r;
            float s = redsum[0][row16] + redsum[1][row16]
                    + redsum[2][row16] + redsum[3][row16];
            scl[row16] = 16.0f / s;   // x16 folded into P; undone by 0.9/16 in hop
        }
    }
    __syncthreads();

    // scale -> fp8 pack -> coalesced store. Thread t covers bytes [t*64, +64).
    u8* Pb = P8 + ((size_t)bh << 20) + rt * 16384;
    int cc = threadIdx.x * 2;
    #pragma unroll
    for (int i = 0; i < 2; ++i, ++cc) {
        const int kc = cc >> 4, r = cc & 15;
        const float s = scl[r];
        const u16* ep = &ebuf[r * 1040 + kc * 32];
        unsigned int w[8];
        #pragma unroll
        for (int g = 0; g < 8; ++g) {
            float f0 = b2f(ep[g * 4 + 0]) * s;
            float f1 = b2f(ep[g * 4 + 1]) * s;
            float f2 = b2f(ep[g * 4 + 2]) * s;
            float f3 = b2f(ep[g * 4 + 3]) * s;
            int lo = __builtin_amdgcn_cvt_pk_fp8_f32(f0, f1, 0, false);
            w[g] = (unsigned int)__builtin_amdgcn_cvt_pk_fp8_f32(f2, f3, lo, true);
        }
        uint4 o0; o0.x = w[0]; o0.y = w[1]; o0.z = w[2]; o0.w = w[3];
        uint4 o1; o1.x = w[4]; o1.y = w[5]; o1.z = w[6]; o1.w = w[7];
        *(uint4*)(Pb + cc * 32)      = o0;
        *(uint4*)(Pb + cc * 32 + 16) = o1;
    }
}

// ---------------------------------------------------------------------------
// K3: hop: z' = (0.9/16) * P16 @ z + 0.1 * v.
// last=0: write z'^T fp8;  last=1: write z' bf16 in [b,n,512] layout.
// ---------------------------------------------------------------------------
__global__ __launch_bounds__(512) void hop(
    const u8* __restrict__ P8, const u8* __restrict__ z8in,
    const u16* __restrict__ v, u8* __restrict__ z8out,
    u16* __restrict__ zbf_out, int last)
{
    const int b = blockIdx.z, h = blockIdx.y, rt = blockIdx.x;
    const int bh = b * NHEADS + h;
    const int tid = threadIdx.x;
    const int wave = tid >> 6, lane = tid & 63;
    const int ln = lane & 15, quad = lane >> 4;
    const int wrow = rt * 128 + wave * 16;

    __shared__ __align__(16) u8 zt[64 * 1040];

    const u8* zg = z8in + ((size_t)bh << 16);
    #pragma unroll
    for (int i = 0; i < 8; ++i) {
        int c = wave * 8 + i;
        gl_lds16(zg + (size_t)c * 1024 + lane * 16, (char*)zt + c * 1040);
    }
    __syncthreads();

    f32x4 acc[4];
    #pragma unroll
    for (int ci = 0; ci < 4; ++ci) acc[ci] = (f32x4){0.f, 0.f, 0.f, 0.f};

    const u8* pt = P8 + ((size_t)bh << 20) + (size_t)(rt * 8 + wave) * 16384
                 + ln * 32 + quad * 8;
    #pragma unroll 4
    for (int kc = 0; kc < 32; ++kc) {
        long a = *(const long*)(pt + kc * 512);
        int kk = kc * 32;
        #pragma unroll
        for (int ci = 0; ci < 4; ++ci) {
            long bz = *(const long*)&zt[(ci * 16 + ln) * 1040 + kk + quad * 8];
            acc[ci] = __builtin_amdgcn_mfma_f32_16x16x32_fp8_fp8(a, bz, acc[ci], 0, 0, 0);
        }
    }

    if (last) {
        #pragma unroll
        for (int ci = 0; ci < 4; ++ci) {
            int col = ci * 16 + ln;
            #pragma unroll
            for (int r = 0; r < 4; ++r) {
                int row = wrow + quad * 4 + r;
                float vv = b2f(v[((size_t)bh * NN + row) * UU + col]);
                zbf_out[((size_t)(b * NN + row)) * HH + h * UU + col]
                    = f2b(0.05625f * acc[ci][r] + 0.1f * vv);
            }
        }
    } else {
        u8* zo = z8out + ((size_t)bh << 16);
        #pragma unroll
        for (int ci = 0; ci < 4; ++ci) {
            int col = ci * 16 + ln;
            float zv[4];
            #pragma unroll
            for (int r = 0; r < 4; ++r) {
                int row = wrow + quad * 4 + r;
                float vv = b2f(v[((size_t)bh * NN + row) * UU + col]);
                zv[r] = 0.05625f * acc[ci][r] + 0.1f * vv;
            }
            int lo = __builtin_amdgcn_cvt_pk_fp8_f32(zv[0], zv[1], 0, false);
            unsigned int dw = (unsigned int)__builtin_amdgcn_cvt_pk_fp8_f32(zv[2], zv[3], lo, true);
            *(unsigned int*)&zo[(size_t)col * 1024 + wrow + quad * 4] = dw;
        }
    }
}

// ---------------------------------------------------------------------------
// K4: y = x + z ; LayerNorm(y)*gamma + beta. x fp32, z bf16 [b,n,512], out fp32.
// ---------------------------------------------------------------------------
__global__ __launch_bounds__(256) void resid_ln(
    const float* __restrict__ x, const u16* __restrict__ z,
    const float* __restrict__ gamma, const float* __restrict__ beta,
    float* __restrict__ out)
{
    const int r = blockIdx.x * 4 + (threadIdx.x >> 6);
    const int lane = threadIdx.x & 63;
    const size_t base = (size_t)r * HH + lane * 8;

    const float4* xp = (const float4*)&x[base];
    float4 x0 = xp[0], x1 = xp[1];
    short8 zv = *(const short8*)&z[base];
    float y[8];
    y[0] = x0.x + b2f((u16)zv[0]); y[1] = x0.y + b2f((u16)zv[1]);
    y[2] = x0.z + b2f((u16)zv[2]); y[3] = x0.w + b2f((u16)zv[3]);
    y[4] = x1.x + b2f((u16)zv[4]); y[5] = x1.y + b2f((u16)zv[5]);
    y[6] = x1.z + b2f((u16)zv[6]); y[7] = x1.w + b2f((u16)zv[7]);

    float s = 0.f, sq = 0.f;
    #pragma unroll
    for (int j = 0; j < 8; ++j) { s += y[j]; sq += y[j] * y[j]; }
    #pragma unroll
    for (int off = 32; off >= 1; off >>= 1) {
        s  += __shfl_xor(s, off);
        sq += __shfl_xor(sq, off);
    }
    const float mu = s * (1.0f / HH);
    const float var = sq * (1.0f / HH) - mu * mu;
    const float rstd = rsqrtf(var + 1e-5f);

    const float4* gp = (const float4*)&gamma[lane * 8];
    const float4* bp = (const float4*)&beta[lane * 8];
    float4 g0 = gp[0], g1 = gp[1], b0 = bp[0], b1 = bp[1];

    float4 o0, o1;
    o0.x = (y[0] - mu) * rstd * g0.x + b0.x;
    o0.y = (y[1] - mu) * rstd * g0.y + b0.y;
    o0.z = (y[2] - mu) * rstd * g0.z + b0.z;
    o0.w = (y[3] - mu) * rstd * g0.w + b0.w;
    o1.x = (y[4] - mu) * rstd * g1.x + b1.x;
    o1.y = (y[5] - mu) * rstd * g1.y + b1.y;
    o1.z = (y[6] - mu) * rstd * g1.z + b1.z;
    o1.w = (y[7] - mu) * rstd * g1.w + b1.w;
    float4* op = (float4*)&out[base];
    op[0] = o0; op[1] = o1;
}

// ---------------------------------------------------------------------------
extern "C" void kernel_launch(void* const* d_in, const int* in_sizes, int n_in,
                              void* d_out, int out_size, void* d_ws, size_t ws_size,
                              hipStream_t stream)
{
    const float* x   = (const float*)d_in[0];
    const int* adj   = (const int*)d_in[1];
    const float* Wq  = (const float*)d_in[2];
    const float* bq  = (const float*)d_in[3];
    const float* Wk  = (const float*)d_in[4];
    const float* bk  = (const float*)d_in[5];
    const float* Wv  = (const float*)d_in[6];
    const float* bv  = (const float*)d_in[7];
    const float* gamma = (const float*)d_in[8];
    const float* beta  = (const float*)d_in[9];
    float* out = (float*)d_out;

    const size_t E = (size_t)BB * NN * HH;   // 4,194,304
    u16* ws16 = (u16*)d_ws;
    u16* xb = ws16;
    u16* q  = ws16 + E;      // per-head layout [bh][n][64]
    u16* k  = ws16 + 2 * E;  // per-head layout
    u16* v  = ws16 + 3 * E;  // per-head layout
    u16* za = ws16 + 4 * E;  // final z, bf16, [b,n,512]
    u16* Wb = ws16 + 5 * E;  // 786,432 elems
    u8* base8 = (u8*)(ws16 + 5 * E + 786432);
    u8* P8  = base8;                          // 64 MB, tiled layout
    u8* z8a = base8 + ((size_t)64 << 20);     // 4 MB
    u8* z8b = z8a + ((size_t)4 << 20);        // 4 MB
    u8* v8t = z8b + ((size_t)4 << 20);        // 4 MB
    unsigned int* adjp = (unsigned int*)(v8t + ((size_t)4 << 20));  // 1 MB

    cvt_bf16<<<dim3(2048, 4), 256, 0, stream>>>(x, Wq, Wk, Wv, xb, Wb);
    adj_pack<<<dim3(2048), 256, 0, stream>>>(adj, adjp);
    qkv_gemm<<<dim3(64, 4, 3), 256, 0, stream>>>(xb, Wb, bq, bk, bv, q, k, v);
    vt8<<<dim3(64), 256, 0, stream>>>(v, v8t);
    scores_softmax<<<dim3(64, NHEADS, BB), 256, 0, stream>>>(q, k, adjp, P8);
    hop<<<dim3(8, NHEADS, BB), 512, 0, stream>>>(P8, v8t, v, z8a, za, 0);
    hop<<<dim3(8, NHEADS, BB), 512, 0, stream>>>(P8, z8a, v, z8b, za, 0);
    hop<<<dim3(8, NHEADS, BB), 512, 0, stream>>>(P8, z8b, v, z8a, za, 0);
    hop<<<dim3(8, NHEADS, BB), 512, 0, stream>>>(P8, z8a, v, z8b, za, 1);
    resid_ln<<<dim3(2048), 256, 0, stream>>>(x, za, gamma, beta, out);
}

// Round 9
// 287.937 us; speedup vs baseline: 1.1906x; 1.0839x over previous
//
#include <hip/hip_runtime.h>
#include <hip/hip_bf16.h>

#define BB 8
#define NN 1024
#define HH 512
#define NHEADS 8
#define UU 64

typedef __attribute__((ext_vector_type(8))) short short8;
typedef __attribute__((ext_vector_type(4))) float f32x4;
typedef unsigned short u16;
typedef unsigned char u8;

__device__ inline float b2f(unsigned short u) {
    union { float f; unsigned int i; } c; c.i = ((unsigned int)u) << 16; return c.f;
}
__device__ inline unsigned short f2b(float f) {
    __hip_bfloat16 h = __float2bfloat16(f);
    return *reinterpret_cast<unsigned short*>(&h);
}
// async global->LDS, 16B per lane. lds base wave-uniform; data lands at base + lane*16.
__device__ inline void gl_lds16(const void* g, void* l) {
    __builtin_amdgcn_global_load_lds(
        (const __attribute__((address_space(1))) unsigned int*)g,
        (__attribute__((address_space(3))) unsigned int*)l, 16, 0, 0);
}

// ---------------------------------------------------------------------------
// K0: fp32 -> bf16 for the three W matrices only (x handled inside qkv_gemm).
// ---------------------------------------------------------------------------
__global__ __launch_bounds__(256) void cvt_w(
    const float* __restrict__ Wq, const float* __restrict__ Wk,
    const float* __restrict__ Wv, u16* __restrict__ Wb)
{
    const int which = blockIdx.y;
    const float* src = which == 0 ? Wq : (which == 1 ? Wk : Wv);
    u16* dst = Wb + (size_t)which * HH * HH;
    const int base = (blockIdx.x * 256 + threadIdx.x) * 8;
    const float4* sp = (const float4*)&src[base];
    float4 a = sp[0], b = sp[1];
    short8 o;
    o[0] = (short)f2b(a.x); o[1] = (short)f2b(a.y);
    o[2] = (short)f2b(a.z); o[3] = (short)f2b(a.w);
    o[4] = (short)f2b(b.x); o[5] = (short)f2b(b.y);
    o[6] = (short)f2b(b.z); o[7] = (short)f2b(b.w);
    *(short8*)&dst[base] = o;
}

// ---------------------------------------------------------------------------
// K0b: pack adj (int32 0/1) into bitmask adjp[row(8192)][dword(32)].
// ---------------------------------------------------------------------------
__global__ __launch_bounds__(256) void adj_pack(
    const int* __restrict__ adj, unsigned int* __restrict__ adjp)
{
    const int wave = threadIdx.x >> 6, lane = threadIdx.x & 63;
    const int row = blockIdx.x * 4 + wave;
    const int* ar = adj + (size_t)row * NN;
    unsigned long long* out = (unsigned long long*)(adjp + (size_t)row * 32);
    #pragma unroll
    for (int it = 0; it < 16; ++it) {
        int a = ar[it * 64 + lane];
        unsigned long long m = __ballot(a != 0);
        if (lane == 0) out[it] = m;
    }
}

// ---------------------------------------------------------------------------
// K1: y = x @ W^T + b (q,k,v via blockIdx.z). 128x128 tile, BK=32.
// A staged manually from fp32 x with on-the-fly bf16 cvt (pitch 40);
// B staged via gl_lds16 from pre-converted Wb. LDS-staged C stores.
// Per-head output layout: out[(b*8+h)*1024+n][64].
// ---------------------------------------------------------------------------
__global__ __launch_bounds__(256) void qkv_gemm(
    const float* __restrict__ x, const u16* __restrict__ Wb,
    const float* __restrict__ bq, const float* __restrict__ bk,
    const float* __restrict__ bv,
    u16* __restrict__ q, u16* __restrict__ k, u16* __restrict__ v)
{
    const int which = blockIdx.z;
    const u16* W      = Wb + (size_t)which * HH * HH;
    const float* bias = which == 0 ? bq : (which == 1 ? bk : bv);
    u16* out          = which == 0 ? q  : (which == 1 ? k  : v);

    const int tid = threadIdx.x;
    const int wave = tid >> 6, lane = tid & 63;
    const int ln = lane & 15, quad = lane >> 4;
    const int wr = (wave >> 1) * 64, wc = (wave & 1) * 64;
    const int rowbase = blockIdx.x * 128, colbase = blockIdx.y * 128;

    __shared__ __align__(16) u16 As[128 * 40];
    __shared__ __align__(16) u16 Bs[128 * 32];
    __shared__ __align__(16) u16 Cs[128 * 136];

    f32x4 acc[4][4];
    #pragma unroll
    for (int ri = 0; ri < 4; ++ri)
        #pragma unroll
        for (int ci = 0; ci < 4; ++ci) acc[ri][ci] = (f32x4){0.f, 0.f, 0.f, 0.f};

    const int lr = lane >> 2;          // row-in-16
    const int sg = lane & 3;           // 8-elem k-segment

    for (int kk = 0; kk < HH; kk += 32) {
        __syncthreads();
        #pragma unroll
        for (int i = 0; i < 2; ++i) {
            int r = wave * 32 + i * 16 + lr;
            const float* xp = &x[(size_t)(rowbase + r) * HH + kk + sg * 8];
            float4 f0 = *(const float4*)xp, f1 = *(const float4*)(xp + 4);
            short8 o;
            o[0] = (short)f2b(f0.x); o[1] = (short)f2b(f0.y);
            o[2] = (short)f2b(f0.z); o[3] = (short)f2b(f0.w);
            o[4] = (short)f2b(f1.x); o[5] = (short)f2b(f1.y);
            o[6] = (short)f2b(f1.z); o[7] = (short)f2b(f1.w);
            *(short8*)&As[r * 40 + sg * 8] = o;
            gl_lds16(&W[(size_t)(colbase + r) * HH + kk + sg * 8],
                     (char*)Bs + (wave * 32 + i * 16) * 64);
        }
        __syncthreads();

        short8 bfr[4];
        #pragma unroll
        for (int ci = 0; ci < 4; ++ci)
            bfr[ci] = *(const short8*)&Bs[(wc + ci * 16 + ln) * 32 + quad * 8];
        #pragma unroll
        for (int ri = 0; ri < 4; ++ri) {
            short8 af = *(const short8*)&As[(wr + ri * 16 + ln) * 40 + quad * 8];
            #pragma unroll
            for (int ci = 0; ci < 4; ++ci)
                acc[ri][ci] = __builtin_amdgcn_mfma_f32_16x16x32_bf16(af, bfr[ci], acc[ri][ci], 0, 0, 0);
        }
    }

    #pragma unroll
    for (int ci = 0; ci < 4; ++ci) {
        int col = wc + ci * 16 + ln;
        float bb = bias[colbase + col];
        #pragma unroll
        for (int ri = 0; ri < 4; ++ri) {
            #pragma unroll
            for (int r = 0; r < 4; ++r) {
                int row = wr + ri * 16 + quad * 4 + r;
                Cs[row * 136 + col] = f2b(acc[ri][ci][r] + bb);
            }
        }
    }
    __syncthreads();
    {
        int row = tid >> 1, half = tid & 1;
        int gcol0 = colbase + half * 64;
        int hh = gcol0 >> 6;
        int grow = rowbase + row;
        int bidx = grow >> 10, n = grow & 1023;
        u16* op = &out[(((size_t)(bidx * NHEADS + hh)) * NN + n) * UU];
        const u16* cp = &Cs[row * 136 + half * 64];
        #pragma unroll
        for (int j = 0; j < 8; ++j)
            *(short8*)(op + j * 8) = *(const short8*)(cp + j * 8);
    }
}

// ---------------------------------------------------------------------------
// K2b: v (per-head bf16 [bh][n][64]) -> v^T fp8: v8t[bh][d(64)][n(1024)].
// 256 blocks: bh = bx>>2, n-chunks (bx&3)*4 .. +4.
// ---------------------------------------------------------------------------
__global__ __launch_bounds__(256) void vt8(
    const u16* __restrict__ v, u8* __restrict__ v8t)
{
    const int bh = blockIdx.x >> 2, part = blockIdx.x & 3;
    const int t = threadIdx.x;
    const size_t hd = (size_t)bh << 16;
    __shared__ u16 tile[64][72];

    for (int chunk = part * 4; chunk < part * 4 + 4; ++chunk) {
        const int n0 = chunk * 64;
        const int r = t >> 2, cs = t & 3;
        const u16* vp = &v[((size_t)bh * NN + n0 + r) * UU + cs * 16];
        short8 a = *(const short8*)vp;
        short8 b8 = *(const short8*)(vp + 8);
        #pragma unroll
        for (int j = 0; j < 8; ++j) {
            tile[r][cs * 16 + j] = (u16)a[j];
            tile[r][cs * 16 + 8 + j] = (u16)b8[j];
        }
        __syncthreads();
        const int c = t & 63, qt = t >> 6;
        unsigned int w[4];
        #pragma unroll
        for (int g = 0; g < 4; ++g) {
            float f0 = b2f(tile[qt * 16 + g * 4 + 0][c]);
            float f1 = b2f(tile[qt * 16 + g * 4 + 1][c]);
            float f2 = b2f(tile[qt * 16 + g * 4 + 2][c]);
            float f3 = b2f(tile[qt * 16 + g * 4 + 3][c]);
            int lo = __builtin_amdgcn_cvt_pk_fp8_f32(f0, f1, 0, false);
            w[g] = (unsigned int)__builtin_amdgcn_cvt_pk_fp8_f32(f2, f3, lo, true);
        }
        uint4 o; o.x = w[0]; o.y = w[1]; o.z = w[2]; o.w = w[3];
        *(uint4*)&v8t[hd + (size_t)c * 1024 + n0 + qt * 16] = o;
        __syncthreads();
    }
}

// ---------------------------------------------------------------------------
// K2: scores+softmax, 64-row blocks, two-pass flash-style.
// Per (b,h,rt64): wave w owns rows rt*64+w*16..+16.
// k staged per 128-col chunk in padded LDS (pitch 72); pass 1 computes
// row-sums only; pass 2 recomputes, scales, packs fp8 via wave-private
// ebuf (pitch 136 — 128 cols + pad) -> fully coalesced tiled-P stores.
// P8 layout: [bh][tile16(64)][kc(32)][r16(16)][cb(32)].
// ---------------------------------------------------------------------------
__global__ __launch_bounds__(256) void scores_softmax(
    const u16* __restrict__ q, const u16* __restrict__ kmat,
    const unsigned int* __restrict__ adjp, u8* __restrict__ P8)
{
    const int b = blockIdx.z, h = blockIdx.y, rt = blockIdx.x;  // rt: 0..15
    const int bh = b * NHEADS + h;
    const int tid = threadIdx.x;
    const int wave = tid >> 6, lane = tid & 63;
    const int ln = lane & 15, quad = lane >> 4;
    const int wrow = rt * 64 + wave * 16;           // wave's first row

    __shared__ __align__(16) u16 ks[128 * 72];      // k chunk (128 rows), padded
    __shared__ __align__(16) u16 eb[64 * 136];      // e bf16: 64 rows x 128 cols (+8 pad)

    const u16* qp = &q[((size_t)bh * NN + wrow + ln) * UU + quad * 8];
    short8 a0 = *(const short8*)qp;
    short8 a1 = *(const short8*)(qp + 32);

    float rsum[4] = {0.f, 0.f, 0.f, 0.f};
    float scl[4];

    const int srow = tid >> 3;         // 0..31 staging row-in-32
    const int sseg = tid & 7;          // 16B segment

    for (int pass = 0; pass < 2; ++pass) {
        for (int cc = 0; cc < 8; ++cc) {           // 128-col chunks
            __syncthreads();
            #pragma unroll
            for (int j = 0; j < 4; ++j) {
                int kr = j * 32 + srow;
                uint4 kv = *(const uint4*)&kmat[((size_t)bh * NN + cc * 128 + kr) * UU + sseg * 8];
                *(uint4*)&ks[kr * 72 + sseg * 8] = kv;
            }
            __syncthreads();

            unsigned int ab[4][4];
            #pragma unroll
            for (int r = 0; r < 4; ++r) {
                int row = wrow + quad * 4 + r;
                *(uint4*)&ab[r][0] =
                    *(const uint4*)&adjp[((size_t)(b * NN + row)) * 32 + cc * 4];
            }

            #pragma unroll
            for (int ct = 0; ct < 8; ++ct) {
                const u16* kp = &ks[(ct * 16 + ln) * 72 + quad * 8];
                short8 b0 = *(const short8*)kp;
                short8 b1 = *(const short8*)(kp + 32);
                f32x4 acc = (f32x4){0.f, 0.f, 0.f, 0.f};
                acc = __builtin_amdgcn_mfma_f32_16x16x32_bf16(a0, b0, acc, 0, 0, 0);
                acc = __builtin_amdgcn_mfma_f32_16x16x32_bf16(a1, b1, acc, 0, 0, 0);
                const int dw = ct >> 1;
                const int bitpos = (ct & 1) * 16 + ln;
                #pragma unroll
                for (int r = 0; r < 4; ++r) {
                    unsigned int on = (ab[r][dw] >> bitpos) & 1u;
                    float e = on ? __expf(acc[r] - 32.0f) : 0.0f;
                    if (pass == 0) rsum[r] += e;
                    else eb[(wave * 16 + quad * 4 + r) * 136 + ct * 16 + ln] = f2b(e * scl[r]);
                }
            }

            if (pass == 1) {
                // wave-private pack: lane l -> (kc'=l>>4 of 4, r16=l&15), 32 B out
                const int kcp = lane >> 4, r16 = lane & 15;
                const u16* ep = &eb[(wave * 16 + r16) * 136 + kcp * 32];
                unsigned int w[8];
                #pragma unroll
                for (int g2 = 0; g2 < 4; ++g2) {
                    short8 ev = *(const short8*)(ep + g2 * 8);
                    float f0 = b2f((u16)ev[0]);
                    float f1 = b2f((u16)ev[1]);
                    float f2 = b2f((u16)ev[2]);
                    float f3 = b2f((u16)ev[3]);
                    int lo = __builtin_amdgcn_cvt_pk_fp8_f32(f0, f1, 0, false);
                    w[g2 * 2] = (unsigned int)__builtin_amdgcn_cvt_pk_fp8_f32(f2, f3, lo, true);
                    f0 = b2f((u16)ev[4]);
                    f1 = b2f((u16)ev[5]);
                    f2 = b2f((u16)ev[6]);
                    f3 = b2f((u16)ev[7]);
                    lo = __builtin_amdgcn_cvt_pk_fp8_f32(f0, f1, 0, false);
                    w[g2 * 2 + 1] = (unsigned int)__builtin_amdgcn_cvt_pk_fp8_f32(f2, f3, lo, true);
                }
                u8* op = P8 + ((size_t)bh << 20) + (size_t)(rt * 4 + wave) * 16384
                       + (cc * 4 + kcp) * 512 + r16 * 32;
                uint4 o0; o0.x = w[0]; o0.y = w[1]; o0.z = w[2]; o0.w = w[3];
                uint4 o1; o1.x = w[4]; o1.y = w[5]; o1.z = w[6]; o1.w = w[7];
                *(uint4*)op = o0;
                *(uint4*)(op + 16) = o1;
            }
        }
        if (pass == 0) {
            #pragma unroll
            for (int r = 0; r < 4; ++r) {
                #pragma unroll
                for (int off = 8; off >= 1; off >>= 1)
                    rsum[r] += __shfl_xor(rsum[r], off);
                scl[r] = 16.0f / rsum[r];   // x16 folded; undone by 0.9/16 in hop
            }
        }
    }
}

// ---------------------------------------------------------------------------
// K3: hop: z' = (0.9/16) * P16 @ z + 0.1 * v.
// last=0: write z'^T fp8;  last=1: write z' bf16 in [b,n,512] layout.
// ---------------------------------------------------------------------------
__global__ __launch_bounds__(512) void hop(
    const u8* __restrict__ P8, const u8* __restrict__ z8in,
    const u16* __restrict__ v, u8* __restrict__ z8out,
    u16* __restrict__ zbf_out, int last)
{
    const int b = blockIdx.z, h = blockIdx.y, rt = blockIdx.x;
    const int bh = b * NHEADS + h;
    const int tid = threadIdx.x;
    const int wave = tid >> 6, lane = tid & 63;
    const int ln = lane & 15, quad = lane >> 4;
    const int wrow = rt * 128 + wave * 16;

    __shared__ __align__(16) u8 zt[64 * 1040];

    const u8* zg = z8in + ((size_t)bh << 16);
    #pragma unroll
    for (int i = 0; i < 8; ++i) {
        int c = wave * 8 + i;
        gl_lds16(zg + (size_t)c * 1024 + lane * 16, (char*)zt + c * 1040);
    }
    __syncthreads();

    f32x4 acc[4];
    #pragma unroll
    for (int ci = 0; ci < 4; ++ci) acc[ci] = (f32x4){0.f, 0.f, 0.f, 0.f};

    const u8* pt = P8 + ((size_t)bh << 20) + (size_t)(rt * 8 + wave) * 16384
                 + ln * 32 + quad * 8;
    #pragma unroll 4
    for (int kc = 0; kc < 32; ++kc) {
        long a = *(const long*)(pt + kc * 512);
        int kk = kc * 32;
        #pragma unroll
        for (int ci = 0; ci < 4; ++ci) {
            long bz = *(const long*)&zt[(ci * 16 + ln) * 1040 + kk + quad * 8];
            acc[ci] = __builtin_amdgcn_mfma_f32_16x16x32_fp8_fp8(a, bz, acc[ci], 0, 0, 0);
        }
    }

    if (last) {
        #pragma unroll
        for (int ci = 0; ci < 4; ++ci) {
            int col = ci * 16 + ln;
            #pragma unroll
            for (int r = 0; r < 4; ++r) {
                int row = wrow + quad * 4 + r;
                float vv = b2f(v[((size_t)bh * NN + row) * UU + col]);
                zbf_out[((size_t)(b * NN + row)) * HH + h * UU + col]
                    = f2b(0.05625f * acc[ci][r] + 0.1f * vv);
            }
        }
    } else {
        u8* zo = z8out + ((size_t)bh << 16);
        #pragma unroll
        for (int ci = 0; ci < 4; ++ci) {
            int col = ci * 16 + ln;
            float zv[4];
            #pragma unroll
            for (int r = 0; r < 4; ++r) {
                int row = wrow + quad * 4 + r;
                float vv = b2f(v[((size_t)bh * NN + row) * UU + col]);
                zv[r] = 0.05625f * acc[ci][r] + 0.1f * vv;
            }
            int lo = __builtin_amdgcn_cvt_pk_fp8_f32(zv[0], zv[1], 0, false);
            unsigned int dw = (unsigned int)__builtin_amdgcn_cvt_pk_fp8_f32(zv[2], zv[3], lo, true);
            *(unsigned int*)&zo[(size_t)col * 1024 + wrow + quad * 4] = dw;
        }
    }
}

// ---------------------------------------------------------------------------
// K4: y = x + z ; LayerNorm(y)*gamma + beta. x fp32, z bf16 [b,n,512], out fp32.
// ---------------------------------------------------------------------------
__global__ __launch_bounds__(256) void resid_ln(
    const float* __restrict__ x, const u16* __restrict__ z,
    const float* __restrict__ gamma, const float* __restrict__ beta,
    float* __restrict__ out)
{
    const int r = blockIdx.x * 4 + (threadIdx.x >> 6);
    const int lane = threadIdx.x & 63;
    const size_t base = (size_t)r * HH + lane * 8;

    const float4* xp = (const float4*)&x[base];
    float4 x0 = xp[0], x1 = xp[1];
    short8 zv = *(const short8*)&z[base];
    float y[8];
    y[0] = x0.x + b2f((u16)zv[0]); y[1] = x0.y + b2f((u16)zv[1]);
    y[2] = x0.z + b2f((u16)zv[2]); y[3] = x0.w + b2f((u16)zv[3]);
    y[4] = x1.x + b2f((u16)zv[4]); y[5] = x1.y + b2f((u16)zv[5]);
    y[6] = x1.z + b2f((u16)zv[6]); y[7] = x1.w + b2f((u16)zv[7]);

    float s = 0.f, sq = 0.f;
    #pragma unroll
    for (int j = 0; j < 8; ++j) { s += y[j]; sq += y[j] * y[j]; }
    #pragma unroll
    for (int off = 32; off >= 1; off >>= 1) {
        s  += __shfl_xor(s, off);
        sq += __shfl_xor(sq, off);
    }
    const float mu = s * (1.0f / HH);
    const float var = sq * (1.0f / HH) - mu * mu;
    const float rstd = rsqrtf(var + 1e-5f);

    const float4* gp = (const float4*)&gamma[lane * 8];
    const float4* bp = (const float4*)&beta[lane * 8];
    float4 g0 = gp[0], g1 = gp[1], b0 = bp[0], b1 = bp[1];

    float4 o0, o1;
    o0.x = (y[0] - mu) * rstd * g0.x + b0.x;
    o0.y = (y[1] - mu) * rstd * g0.y + b0.y;
    o0.z = (y[2] - mu) * rstd * g0.z + b0.z;
    o0.w = (y[3] - mu) * rstd * g0.w + b0.w;
    o1.x = (y[4] - mu) * rstd * g1.x + b1.x;
    o1.y = (y[5] - mu) * rstd * g1.y + b1.y;
    o1.z = (y[6] - mu) * rstd * g1.z + b1.z;
    o1.w = (y[7] - mu) * rstd * g1.w + b1.w;
    float4* op = (float4*)&out[base];
    op[0] = o0; op[1] = o1;
}

// ---------------------------------------------------------------------------
extern "C" void kernel_launch(void* const* d_in, const int* in_sizes, int n_in,
                              void* d_out, int out_size, void* d_ws, size_t ws_size,
                              hipStream_t stream)
{
    const float* x   = (const float*)d_in[0];
    const int* adj   = (const int*)d_in[1];
    const float* Wq  = (const float*)d_in[2];
    const float* bq  = (const float*)d_in[3];
    const float* Wk  = (const float*)d_in[4];
    const float* bk  = (const float*)d_in[5];
    const float* Wv  = (const float*)d_in[6];
    const float* bv  = (const float*)d_in[7];
    const float* gamma = (const float*)d_in[8];
    const float* beta  = (const float*)d_in[9];
    float* out = (float*)d_out;

    const size_t E = (size_t)BB * NN * HH;   // 4,194,304
    u16* ws16 = (u16*)d_ws;
    u16* q  = ws16 + E;      // per-head layout [bh][n][64]
    u16* k  = ws16 + 2 * E;  // per-head layout
    u16* v  = ws16 + 3 * E;  // per-head layout
    u16* za = ws16 + 4 * E;  // final z, bf16, [b,n,512]
    u16* Wb = ws16 + 5 * E;  // 786,432 elems
    u8* base8 = (u8*)(ws16 + 5 * E + 786432);
    u8* P8  = base8;                          // 64 MB, tiled layout
    u8* z8a = base8 + ((size_t)64 << 20);     // 4 MB
    u8* z8b = z8a + ((size_t)4 << 20);        // 4 MB
    u8* v8t = z8b + ((size_t)4 << 20);        // 4 MB
    unsigned int* adjp = (unsigned int*)(v8t + ((size_t)4 << 20));  // 1 MB

    cvt_w<<<dim3(128, 3), 256, 0, stream>>>(Wq, Wk, Wv, Wb);
    adj_pack<<<dim3(2048), 256, 0, stream>>>(adj, adjp);
    qkv_gemm<<<dim3(64, 4, 3), 256, 0, stream>>>(x, Wb, bq, bk, bv, q, k, v);
    vt8<<<dim3(256), 256, 0, stream>>>(v, v8t);
    scores_softmax<<<dim3(16, NHEADS, BB), 256, 0, stream>>>(q, k, adjp, P8);
    hop<<<dim3(8, NHEADS, BB), 512, 0, stream>>>(P8, v8t, v, z8a, za, 0);
    hop<<<dim3(8, NHEADS, BB), 512, 0, stream>>>(P8, z8a, v, z8b, za, 0);
    hop<<<dim3(8, NHEADS, BB), 512, 0, stream>>>(P8, z8b, v, z8a, za, 0);
    hop<<<dim3(8, NHEADS, BB), 512, 0, stream>>>(P8, z8a, v, z8b, za, 1);
    resid_ln<<<dim3(2048), 256, 0, stream>>>(x, za, gamma, beta, out);
}